// Round 1
// baseline (1078.421 us; speedup 1.0000x reference)
//
#include <hip/hip_runtime.h>
#include <hip/hip_fp16.h>

#define EPSF 1e-8f

// B=16, L=4096, I=64, H=512, O=1. M = B*L = 65536. CHUNK=64, NC=64.

__device__ __forceinline__ float sigmoidf_(float x) {
    return 1.0f / (1.0f + __expf(-x));
}
__device__ __forceinline__ float tanh_fast(float x) {  // x in (0,1)
    float e = __expf(-2.0f * x);
    return (1.0f - e) / (1.0f + e);
}

// transform pre-activations -> (a, b) of recurrence h = a*h + b
__device__ __forceinline__ void gate_transform(float pz, float ph, float& a, float& b) {
    float k = sigmoidf_(pz);          // k = sigmoid(x@Wz+bz)
    float z = sigmoidf_(k);           // z = sigmoid(k)   (faithful double-sigmoid)
    a = 1.0f - z;                     // exp(-softplus(k))
    float hw = tanh_fast(sigmoidf_(ph)) + EPSF;  // log_g(sigmoid(x@Wh+bh))
    b = z * hw;
}

// ---------------- K1: layer-0 GEMM (K=64) + transform + chunk summaries ----------
// grid.x = M/64 = 1024 blocks, 256 threads. Each block: 64 rows x all 512 cols.
// Thread handles cols h = 2*tid, 2*tid+1.
__global__ __launch_bounds__(256) void k1_layer0(
    const float* __restrict__ x, const float* __restrict__ Wz,
    const float* __restrict__ bz, const float* __restrict__ Wh,
    const float* __restrict__ bh,
    __half* __restrict__ a0, __half* __restrict__ b0,
    float* __restrict__ sumA, float* __restrict__ sumB)
{
    __shared__ float xs[64][64];
    const int tid = threadIdx.x;
    const int m0 = blockIdx.x * 64;

    // stage x tile [64][64]
    const float4* xg = (const float4*)(x + (size_t)m0 * 64);
    float4* xsv = (float4*)(&xs[0][0]);
#pragma unroll
    for (int i = 0; i < 4; ++i) xsv[tid + i * 256] = xg[tid + i * 256];
    __syncthreads();

    const int h0c = 2 * tid;
    const float2 bzv = *(const float2*)&bz[h0c];
    const float2 bhv = *(const float2*)&bh[h0c];

    float Arun0 = 1.f, Brun0 = 0.f, Arun1 = 1.f, Brun1 = 0.f;

    for (int mc = 0; mc < 8; ++mc) {
        float accz0[8] = {}, accz1[8] = {}, acch0[8] = {}, acch1[8] = {};
#pragma unroll 4
        for (int k = 0; k < 64; ++k) {
            float2 wz = *(const float2*)&Wz[k * 512 + h0c];
            float2 wh = *(const float2*)&Wh[k * 512 + h0c];
#pragma unroll
            for (int i = 0; i < 8; ++i) {
                float xv = xs[mc * 8 + i][k];
                accz0[i] = fmaf(xv, wz.x, accz0[i]);
                accz1[i] = fmaf(xv, wz.y, accz1[i]);
                acch0[i] = fmaf(xv, wh.x, acch0[i]);
                acch1[i] = fmaf(xv, wh.y, acch1[i]);
            }
        }
        const int row = m0 + mc * 8;
#pragma unroll
        for (int i = 0; i < 8; ++i) {  // ascending t
            float a_0, b_0, a_1, b_1;
            gate_transform(accz0[i] + bzv.x, acch0[i] + bhv.x, a_0, b_0);
            gate_transform(accz1[i] + bzv.y, acch1[i] + bhv.y, a_1, b_1);
            size_t off = ((size_t)(row + i) * 512 + h0c) >> 1;  // half2 index
            ((__half2*)a0)[off] = __floats2half2_rn(a_0, a_1);
            ((__half2*)b0)[off] = __floats2half2_rn(b_0, b_1);
            Brun0 = fmaf(a_0, Brun0, b_0); Arun0 *= a_0;
            Brun1 = fmaf(a_1, Brun1, b_1); Arun1 *= a_1;
        }
    }
    const int bidx = m0 >> 12;            // / 4096
    const int chunk = (m0 & 4095) >> 6;   // / 64
    const size_t so = ((size_t)(bidx * 64 + chunk) << 9) + h0c;
    *(float2*)&sumA[so] = make_float2(Arun0, Arun1);
    *(float2*)&sumB[so] = make_float2(Brun0, Brun1);
}

// ---------------- K2: scan chunk summaries -> per-chunk carry-in ------------------
// 8192 threads = (b,h). 64 sequential chunk steps.
__global__ __launch_bounds__(256) void k2_carry(
    const float* __restrict__ sumA, const float* __restrict__ sumB,
    float* __restrict__ carry)
{
    const int idx = blockIdx.x * 256 + threadIdx.x;  // 0..8191
    const int b = idx >> 9, h = idx & 511;
    float H = EPSF;
    for (int c = 0; c < 64; ++c) {
        const size_t o = ((size_t)(b * 64 + c) << 9) + h;
        carry[o] = H;
        H = fmaf(sumA[o], H, sumB[o]);
    }
}

// ---------------- K3: apply carries, materialize h0 (fp16) ------------------------
// 1024 blocks = (b, c); 256 threads; each thread 2 adjacent h via half2.
__global__ __launch_bounds__(256) void k3_h0(
    const __half* __restrict__ a0, const __half* __restrict__ b0,
    const float* __restrict__ carry, __half* __restrict__ h0)
{
    const int tid = threadIdx.x;
    const int c = blockIdx.x & 63, b = blockIdx.x >> 6;
    const size_t co = ((size_t)(b * 64 + c) << 9) + tid * 2;
    float2 H = *(const float2*)&carry[co];
    const size_t base2 = (((size_t)(b * 4096 + c * 64) << 9) >> 1) + tid;  // half2 index
    const __half2* a2 = (const __half2*)a0;
    const __half2* b2 = (const __half2*)b0;
    __half2* h2 = (__half2*)h0;
    for (int i = 0; i < 64; ++i) {
        const size_t o = base2 + (size_t)i * 256;
        float2 a = __half22float2(a2[o]);
        float2 bb = __half22float2(b2[o]);
        H.x = fmaf(a.x, H.x, bb.x);
        H.y = fmaf(a.y, H.y, bb.y);
        h2[o] = __float22half2_rn(H);
    }
}

// ---------------- K4: layer-1 GEMMs (fp32, K=512) + transform + chunk summaries ---
// grid = (8 n-tiles, 1024 m-tiles); block 256 (16x16), micro 4x4, two GEMMs fused.
#define LDA 68
__global__ __launch_bounds__(256) void k4_layer1(
    const __half* __restrict__ h0,
    const float* __restrict__ Wz, const float* __restrict__ bz,
    const float* __restrict__ Wh, const float* __restrict__ bh,
    float* __restrict__ sumA, float* __restrict__ sumB)
{
    __shared__ float As[32][LDA];
    __shared__ float Bzs[32][64];
    __shared__ float Bhs[32][64];
    __shared__ float partA[16][64];
    __shared__ float partB[16][64];

    const int tid = threadIdx.x;
    const int tx = tid & 15, ty = tid >> 4;
    const int m0 = blockIdx.y * 64, n0 = blockIdx.x * 64;

    float accz[4][4] = {}; float acch[4][4] = {};

    const int arow = tid >> 2;        // 0..63
    const int ak8 = (tid & 3) * 8;    // 0,8,16,24

    for (int k0 = 0; k0 < 512; k0 += 32) {
        __syncthreads();
        {   // A: 64 rows x 32 k (half -> float, transposed)
            const __half* ap = h0 + (size_t)(m0 + arow) * 512 + k0 + ak8;
            uint4 raw = *(const uint4*)ap;
            const __half2* hp = (const __half2*)&raw;
#pragma unroll
            for (int j = 0; j < 4; ++j) {
                float2 f = __half22float2(hp[j]);
                As[ak8 + 2 * j][arow] = f.x;
                As[ak8 + 2 * j + 1][arow] = f.y;
            }
        }
#pragma unroll
        for (int i = 0; i < 2; ++i) {  // B tiles: 32k x 64n each
            const int f = tid + i * 256;
            const int kk = f >> 4, n4 = (f & 15) * 4;
            *(float4*)&Bzs[kk][n4] = *(const float4*)&Wz[(size_t)(k0 + kk) * 512 + n0 + n4];
            *(float4*)&Bhs[kk][n4] = *(const float4*)&Wh[(size_t)(k0 + kk) * 512 + n0 + n4];
        }
        __syncthreads();
#pragma unroll 4
        for (int kk = 0; kk < 32; ++kk) {
            float4 a4 = *(const float4*)&As[kk][ty * 4];
            float4 bz4 = *(const float4*)&Bzs[kk][tx * 4];
            float4 bh4 = *(const float4*)&Bhs[kk][tx * 4];
            float av[4] = {a4.x, a4.y, a4.z, a4.w};
            float bzv_[4] = {bz4.x, bz4.y, bz4.z, bz4.w};
            float bhv_[4] = {bh4.x, bh4.y, bh4.z, bh4.w};
#pragma unroll
            for (int i = 0; i < 4; ++i)
#pragma unroll
                for (int j = 0; j < 4; ++j) {
                    accz[i][j] = fmaf(av[i], bzv_[j], accz[i][j]);
                    acch[i][j] = fmaf(av[i], bhv_[j], acch[i][j]);
                }
        }
    }

    // epilogue: transform + per-thread partial affine over its 4 consecutive rows
    float bzv[4], bhv[4];
#pragma unroll
    for (int j = 0; j < 4; ++j) {
        bzv[j] = bz[n0 + tx * 4 + j];
        bhv[j] = bh[n0 + tx * 4 + j];
    }
    float pA[4] = {1.f, 1.f, 1.f, 1.f}, pB[4] = {0.f, 0.f, 0.f, 0.f};
#pragma unroll
    for (int i = 0; i < 4; ++i) {   // ascending t within thread
#pragma unroll
        for (int j = 0; j < 4; ++j) {
            float a, b;
            gate_transform(accz[i][j] + bzv[j], acch[i][j] + bhv[j], a, b);
            pB[j] = fmaf(a, pB[j], b);
            pA[j] *= a;
        }
    }
#pragma unroll
    for (int j = 0; j < 4; ++j) {
        partA[ty][tx * 4 + j] = pA[j];
        partB[ty][tx * 4 + j] = pB[j];
    }
    __syncthreads();
    if (tid < 64) {  // compose 16 pieces (ascending t) for column n0+tid
        float Ar = 1.f, Br = 0.f;
#pragma unroll
        for (int t = 0; t < 16; ++t) {
            float pa = partA[t][tid], pb = partB[t][tid];
            Br = fmaf(pa, Br, pb);
            Ar *= pa;
        }
        const int bidx = m0 >> 12;
        const int chunk = (m0 & 4095) >> 6;
        const size_t o = ((size_t)(bidx * 64 + chunk) << 9) + n0 + tid;
        sumA[o] = Ar;
        sumB[o] = Br;
    }
}

// ---------------- K5: final chunk scan + GEMV with Wf ----------------------------
__global__ __launch_bounds__(512) void k5_final(
    const float* __restrict__ sumA, const float* __restrict__ sumB,
    const float* __restrict__ Wf, const float* __restrict__ bf,
    float* __restrict__ out)
{
    const int b = blockIdx.x, h = threadIdx.x;
    float H = EPSF;
    for (int c = 0; c < 64; ++c) {
        const size_t o = ((size_t)(b * 64 + c) << 9) + h;
        H = fmaf(sumA[o], H, sumB[o]);
    }
    float v = H * Wf[h];
#pragma unroll
    for (int off = 32; off; off >>= 1) v += __shfl_down(v, off, 64);
    __shared__ float wsum[8];
    if ((h & 63) == 0) wsum[h >> 6] = v;
    __syncthreads();
    if (h == 0) {
        float s = 0.f;
#pragma unroll
        for (int i = 0; i < 8; ++i) s += wsum[i];
        out[b] = s + bf[0];
    }
}

extern "C" void kernel_launch(void* const* d_in, const int* in_sizes, int n_in,
                              void* d_out, int out_size, void* d_ws, size_t ws_size,
                              hipStream_t stream)
{
    const float* x   = (const float*)d_in[0];
    const float* Wz0 = (const float*)d_in[1];
    const float* bz0 = (const float*)d_in[2];
    const float* Wh0 = (const float*)d_in[3];
    const float* bh0 = (const float*)d_in[4];
    const float* Wz1 = (const float*)d_in[5];
    const float* bz1 = (const float*)d_in[6];
    const float* Wh1 = (const float*)d_in[7];
    const float* bh1 = (const float*)d_in[8];
    const float* Wf  = (const float*)d_in[9];
    const float* bf  = (const float*)d_in[10];
    float* out = (float*)d_out;

    // workspace layout (needs ~203 MiB)
    char* ws = (char*)d_ws;
    const size_t SZ_HALF = (size_t)16 * 4096 * 512 * 2;  // 64 MiB per fp16 tensor
    __half* a0 = (__half*)(ws);
    __half* b0 = (__half*)(ws + SZ_HALF);
    __half* h0 = (__half*)(ws + 2 * SZ_HALF);
    float* sumA0  = (float*)(ws + 3 * SZ_HALF);
    float* sumB0  = sumA0 + 524288;
    float* carry0 = sumB0 + 524288;
    float* sumA1  = carry0 + 524288;
    float* sumB1  = sumA1 + 524288;

    k1_layer0<<<1024, 256, 0, stream>>>(x, Wz0, bz0, Wh0, bh0, a0, b0, sumA0, sumB0);
    k2_carry<<<32, 256, 0, stream>>>(sumA0, sumB0, carry0);
    k3_h0<<<1024, 256, 0, stream>>>(a0, b0, carry0, h0);
    dim3 g4(8, 1024);
    k4_layer1<<<g4, 256, 0, stream>>>(h0, Wz1, bz1, Wh1, bh1, sumA1, sumB1);
    k5_final<<<16, 512, 0, stream>>>(sumA1, sumB1, Wf, bf, out);
}

// Round 2
// 564.576 us; speedup vs baseline: 1.9101x; 1.9101x over previous
//
#include <hip/hip_runtime.h>
#include <hip/hip_fp16.h>

#define EPSF 1e-8f

typedef _Float16 half8 __attribute__((ext_vector_type(8)));
typedef float f32x4 __attribute__((ext_vector_type(4)));

// B=16, L=4096, I=64, H=512, O=1. M = B*L = 65536. CHUNK=64, NC=64.

__device__ __forceinline__ float sigmoidf_(float x) {
    return 1.0f / (1.0f + __expf(-x));
}
__device__ __forceinline__ float tanh_fast(float x) {  // x in (0,1)
    float e = __expf(-2.0f * x);
    return (1.0f - e) / (1.0f + e);
}

// transform pre-activations -> (a, b) of recurrence h = a*h + b
__device__ __forceinline__ void gate_transform(float pz, float ph, float& a, float& b) {
    float k = sigmoidf_(pz);          // k = sigmoid(x@Wz+bz)
    float z = sigmoidf_(k);           // z = sigmoid(k)   (faithful double-sigmoid)
    a = 1.0f - z;                     // exp(-softplus(k))
    float hw = tanh_fast(sigmoidf_(ph)) + EPSF;  // log_g(sigmoid(x@Wh+bh))
    b = z * hw;
}

// ---------------- K0: transpose+convert W [512k][512n] f32 -> Wt [n][k] fp16 ------
__global__ __launch_bounds__(256) void k0_convw(
    const float* __restrict__ W, __half* __restrict__ Wt)
{
    __shared__ float t[64][65];
    const int n0 = blockIdx.x * 64, k0 = blockIdx.y * 64;
    const int tid = threadIdx.x;
    const int r = tid >> 4, c4 = (tid & 15) * 4;
#pragma unroll
    for (int rr = 0; rr < 64; rr += 16)
        *(float4*)&t[rr + r][c4] = *(const float4*)&W[(size_t)(k0 + rr + r) * 512 + n0 + c4];
    __syncthreads();
#pragma unroll
    for (int rr = 0; rr < 64; rr += 16) {
        const int row = rr + r;
        __half2 h01 = __floats2half2_rn(t[c4 + 0][row], t[c4 + 1][row]);
        __half2 h23 = __floats2half2_rn(t[c4 + 2][row], t[c4 + 3][row]);
        *(__half2*)&Wt[(size_t)(n0 + row) * 512 + k0 + c4] = h01;
        *(__half2*)&Wt[(size_t)(n0 + row) * 512 + k0 + c4 + 2] = h23;
    }
}

// ---------------- K1: layer-0 GEMM (K=64) + transform + chunk summaries ----------
__global__ __launch_bounds__(256) void k1_layer0(
    const float* __restrict__ x, const float* __restrict__ Wz,
    const float* __restrict__ bz, const float* __restrict__ Wh,
    const float* __restrict__ bh,
    __half* __restrict__ a0, __half* __restrict__ b0,
    float* __restrict__ sumA, float* __restrict__ sumB)
{
    __shared__ float xs[64][64];
    const int tid = threadIdx.x;
    const int m0 = blockIdx.x * 64;

    const float4* xg = (const float4*)(x + (size_t)m0 * 64);
    float4* xsv = (float4*)(&xs[0][0]);
#pragma unroll
    for (int i = 0; i < 4; ++i) xsv[tid + i * 256] = xg[tid + i * 256];
    __syncthreads();

    const int h0c = 2 * tid;
    const float2 bzv = *(const float2*)&bz[h0c];
    const float2 bhv = *(const float2*)&bh[h0c];

    float Arun0 = 1.f, Brun0 = 0.f, Arun1 = 1.f, Brun1 = 0.f;

    for (int mc = 0; mc < 8; ++mc) {
        float accz0[8] = {}, accz1[8] = {}, acch0[8] = {}, acch1[8] = {};
#pragma unroll 4
        for (int k = 0; k < 64; ++k) {
            float2 wz = *(const float2*)&Wz[k * 512 + h0c];
            float2 wh = *(const float2*)&Wh[k * 512 + h0c];
#pragma unroll
            for (int i = 0; i < 8; ++i) {
                float xv = xs[mc * 8 + i][k];
                accz0[i] = fmaf(xv, wz.x, accz0[i]);
                accz1[i] = fmaf(xv, wz.y, accz1[i]);
                acch0[i] = fmaf(xv, wh.x, acch0[i]);
                acch1[i] = fmaf(xv, wh.y, acch1[i]);
            }
        }
        const int row = m0 + mc * 8;
#pragma unroll
        for (int i = 0; i < 8; ++i) {  // ascending t
            float a_0, b_0, a_1, b_1;
            gate_transform(accz0[i] + bzv.x, acch0[i] + bhv.x, a_0, b_0);
            gate_transform(accz1[i] + bzv.y, acch1[i] + bhv.y, a_1, b_1);
            size_t off = ((size_t)(row + i) * 512 + h0c) >> 1;  // half2 index
            ((__half2*)a0)[off] = __floats2half2_rn(a_0, a_1);
            ((__half2*)b0)[off] = __floats2half2_rn(b_0, b_1);
            Brun0 = fmaf(a_0, Brun0, b_0); Arun0 *= a_0;
            Brun1 = fmaf(a_1, Brun1, b_1); Arun1 *= a_1;
        }
    }
    const int bidx = m0 >> 12;            // / 4096
    const int chunk = (m0 & 4095) >> 6;   // / 64
    const size_t so = ((size_t)(bidx * 64 + chunk) << 9) + h0c;
    *(float2*)&sumA[so] = make_float2(Arun0, Arun1);
    *(float2*)&sumB[so] = make_float2(Brun0, Brun1);
}

// ---------------- K2: scan chunk summaries -> per-chunk carry-in ------------------
__global__ __launch_bounds__(256) void k2_carry(
    const float* __restrict__ sumA, const float* __restrict__ sumB,
    float* __restrict__ carry)
{
    const int idx = blockIdx.x * 256 + threadIdx.x;  // 0..8191
    const int b = idx >> 9, h = idx & 511;
    float H = EPSF;
    for (int c = 0; c < 64; ++c) {
        const size_t o = ((size_t)(b * 64 + c) << 9) + h;
        carry[o] = H;
        H = fmaf(sumA[o], H, sumB[o]);
    }
}

// ---------------- K3: apply carries, materialize h0 (fp16) ------------------------
__global__ __launch_bounds__(256) void k3_h0(
    const __half* __restrict__ a0, const __half* __restrict__ b0,
    const float* __restrict__ carry, __half* __restrict__ h0)
{
    const int tid = threadIdx.x;
    const int c = blockIdx.x & 63, b = blockIdx.x >> 6;
    const size_t co = ((size_t)(b * 64 + c) << 9) + tid * 2;
    float2 H = *(const float2*)&carry[co];
    const size_t base2 = (((size_t)(b * 4096 + c * 64) << 9) >> 1) + tid;  // half2 index
    const __half2* a2 = (const __half2*)a0;
    const __half2* b2 = (const __half2*)b0;
    __half2* h2 = (__half2*)h0;
    for (int i = 0; i < 64; ++i) {
        const size_t o = base2 + (size_t)i * 256;
        float2 a = __half22float2(a2[o]);
        float2 bb = __half22float2(b2[o]);
        H.x = fmaf(a.x, H.x, bb.x);
        H.y = fmaf(a.y, H.y, bb.y);
        h2[o] = __float22half2_rn(H);
    }
}

// ---------------- K4: layer-1 GEMMs via MFMA fp16 + transform + chunk summaries ---
// grid = (2 n-halves, 1024 m-chunks); block 512 (8 waves).
// Block tile: 64 m x 256 n, both GEMMs (z,h). Wave w: cols w*32..w*32+31 (z and h).
#define BPAD 40  // halfs per LDS row (32 data + 8 pad) = 80 B, 16B-aligned
__global__ __launch_bounds__(512) void k4_layer1(
    const __half* __restrict__ h0,
    const __half* __restrict__ Wtz, const __half* __restrict__ Wth,  // [n][k] fp16
    const float* __restrict__ bz, const float* __restrict__ bh,
    float* __restrict__ sumA, float* __restrict__ sumB)
{
    __shared__ char smem[(64 + 512) * BPAD * 2];   // 46080 B
    __half* As = (__half*)smem;                    // [64][BPAD]
    __half* Bs = (__half*)(smem + 64 * BPAD * 2);  // [512][BPAD] rows<256: z, >=256: h
    float* partA = (float*)smem;                   // overlay after last barrier
    float* partB = partA + 16 * 256;

    const int tid = threadIdx.x;
    const int wave = tid >> 6, lane = tid & 63;
    const int q = lane >> 4, l16 = lane & 15;
    const int m0 = blockIdx.y * 64;
    const int n0 = blockIdx.x * 256;

    f32x4 accz[4][2], acch[4][2];
#pragma unroll
    for (int mi = 0; mi < 4; ++mi)
#pragma unroll
        for (int ni = 0; ni < 2; ++ni) {
            accz[mi][ni] = (f32x4){0.f, 0.f, 0.f, 0.f};
            acch[mi][ni] = (f32x4){0.f, 0.f, 0.f, 0.f};
        }

    // staging addresses
    const __half* asrc = h0 + (size_t)(m0 + (tid >> 2)) * 512 + (tid & 3) * 8;
    const int a_lds = (tid >> 2) * BPAD + (tid & 3) * 8;
    const __half* bsrc[4];
    int b_lds[4];
#pragma unroll
    for (int i = 0; i < 4; ++i) {
        const int idx = tid + i * 512;
        const int brow = idx >> 2, bc = idx & 3;
        const __half* base = (brow < 256) ? (Wtz + (size_t)(n0 + brow) * 512)
                                          : (Wth + (size_t)(n0 + brow - 256) * 512);
        bsrc[i] = base + bc * 8;
        b_lds[i] = brow * BPAD + bc * 8;
    }

    // prologue: prefetch tile 0 into registers
    uint4 pa;
    uint4 pb[4];
    if (tid < 256) pa = *(const uint4*)asrc;
#pragma unroll
    for (int i = 0; i < 4; ++i) pb[i] = *(const uint4*)bsrc[i];

    for (int t = 0; t < 16; ++t) {
        __syncthreads();                 // previous compute done reading LDS
        if (tid < 256) *(uint4*)&As[a_lds] = pa;
#pragma unroll
        for (int i = 0; i < 4; ++i) *(uint4*)&Bs[b_lds[i]] = pb[i];
        if (t < 15) {                    // issue next-tile loads; overlap with MFMA
            const int ko = (t + 1) * 32;
            if (tid < 256) pa = *(const uint4*)(asrc + ko);
#pragma unroll
            for (int i = 0; i < 4; ++i) pb[i] = *(const uint4*)(bsrc[i] + ko);
        }
        __syncthreads();                 // staging visible
        half8 af[4];
#pragma unroll
        for (int mi = 0; mi < 4; ++mi)
            af[mi] = *(const half8*)&As[(mi * 16 + l16) * BPAD + q * 8];
#pragma unroll
        for (int ni = 0; ni < 2; ++ni) {
            const int col = wave * 32 + ni * 16 + l16;
            half8 b_z = *(const half8*)&Bs[(size_t)col * BPAD + q * 8];
            half8 b_h = *(const half8*)&Bs[(size_t)(256 + col) * BPAD + q * 8];
#pragma unroll
            for (int mi = 0; mi < 4; ++mi) {
                accz[mi][ni] = __builtin_amdgcn_mfma_f32_16x16x32_f16(af[mi], b_z, accz[mi][ni], 0, 0, 0);
                acch[mi][ni] = __builtin_amdgcn_mfma_f32_16x16x32_f16(af[mi], b_h, acch[mi][ni], 0, 0, 0);
            }
        }
    }

    // epilogue: gate transform + per-(mi,q) 4-step affine partials
    __syncthreads();   // all waves done reading Bs; safe to overlay
#pragma unroll
    for (int ni = 0; ni < 2; ++ni) {
        const int col = wave * 32 + ni * 16 + l16;   // block-local pz col 0..255
        const float bzv = bz[n0 + col], bhv = bh[n0 + col];
#pragma unroll
        for (int mi = 0; mi < 4; ++mi) {
            float pA = 1.f, pB = 0.f;
#pragma unroll
            for (int j = 0; j < 4; ++j) {            // t = mi*16 + q*4 + j ascending
                float a, b;
                gate_transform(accz[mi][ni][j] + bzv, acch[mi][ni][j] + bhv, a, b);
                pB = fmaf(a, pB, b);
                pA *= a;
            }
            const int seg = mi * 4 + q;              // ascending-t segment index
            partA[seg * 256 + col] = pA;
            partB[seg * 256 + col] = pB;
        }
    }
    __syncthreads();
    if (tid < 256) {
        float Ar = 1.f, Br = 0.f;
#pragma unroll
        for (int s = 0; s < 16; ++s) {
            float a = partA[s * 256 + tid], b = partB[s * 256 + tid];
            Br = fmaf(a, Br, b);
            Ar *= a;
        }
        const int bidx = m0 >> 12, chunk = (m0 & 4095) >> 6;
        const size_t o = ((size_t)(bidx * 64 + chunk) << 9) + n0 + tid;
        sumA[o] = Ar;
        sumB[o] = Br;
    }
}

// ---------------- K5: final chunk scan + GEMV with Wf ----------------------------
__global__ __launch_bounds__(512) void k5_final(
    const float* __restrict__ sumA, const float* __restrict__ sumB,
    const float* __restrict__ Wf, const float* __restrict__ bf,
    float* __restrict__ out)
{
    const int b = blockIdx.x, h = threadIdx.x;
    float H = EPSF;
    for (int c = 0; c < 64; ++c) {
        const size_t o = ((size_t)(b * 64 + c) << 9) + h;
        H = fmaf(sumA[o], H, sumB[o]);
    }
    float v = H * Wf[h];
#pragma unroll
    for (int off = 32; off; off >>= 1) v += __shfl_down(v, off, 64);
    __shared__ float wsum[8];
    if ((h & 63) == 0) wsum[h >> 6] = v;
    __syncthreads();
    if (h == 0) {
        float s = 0.f;
#pragma unroll
        for (int i = 0; i < 8; ++i) s += wsum[i];
        out[b] = s + bf[0];
    }
}

extern "C" void kernel_launch(void* const* d_in, const int* in_sizes, int n_in,
                              void* d_out, int out_size, void* d_ws, size_t ws_size,
                              hipStream_t stream)
{
    const float* x   = (const float*)d_in[0];
    const float* Wz0 = (const float*)d_in[1];
    const float* bz0 = (const float*)d_in[2];
    const float* Wh0 = (const float*)d_in[3];
    const float* bh0 = (const float*)d_in[4];
    const float* Wz1 = (const float*)d_in[5];
    const float* bz1 = (const float*)d_in[6];
    const float* Wh1 = (const float*)d_in[7];
    const float* bh1 = (const float*)d_in[8];
    const float* Wf  = (const float*)d_in[9];
    const float* bf  = (const float*)d_in[10];
    float* out = (float*)d_out;

    // workspace layout (~199 MiB)
    char* ws = (char*)d_ws;
    const size_t SZ_HALF = (size_t)16 * 4096 * 512 * 2;  // 64 MiB per fp16 tensor
    __half* a0 = (__half*)(ws);
    __half* b0 = (__half*)(ws + SZ_HALF);
    __half* h0 = (__half*)(ws + 2 * SZ_HALF);
    float* sumA  = (float*)(ws + 3 * SZ_HALF);   // reused: L0 (k1->k2), then L1 (k4->k5)
    float* sumB  = sumA + 524288;
    float* carry = sumB + 524288;
    __half* Wtz  = (__half*)(carry + 524288);
    __half* Wth  = Wtz + 262144;

    k0_convw<<<dim3(8, 8), 256, 0, stream>>>(Wz1, Wtz);
    k0_convw<<<dim3(8, 8), 256, 0, stream>>>(Wh1, Wth);
    k1_layer0<<<1024, 256, 0, stream>>>(x, Wz0, bz0, Wh0, bh0, a0, b0, sumA, sumB);
    k2_carry<<<32, 256, 0, stream>>>(sumA, sumB, carry);
    k3_h0<<<1024, 256, 0, stream>>>(a0, b0, carry, h0);
    k4_layer1<<<dim3(2, 1024), 512, 0, stream>>>(h0, Wtz, Wth, bz1, bh1, sumA, sumB);
    k5_final<<<16, 512, 0, stream>>>(sumA, sumB, Wf, bf, out);
}

// Round 3
// 353.386 us; speedup vs baseline: 3.0517x; 1.5976x over previous
//
#include <hip/hip_runtime.h>
#include <hip/hip_fp16.h>

#define EPSF 1e-8f

typedef _Float16 half8 __attribute__((ext_vector_type(8)));
typedef float f32x4 __attribute__((ext_vector_type(4)));

// B=16, L=4096, I=64, H=512, O=1. M = B*L = 65536. CHUNK=64, NC=64.

__device__ __forceinline__ float sigmoidf_(float x) {
    return 1.0f / (1.0f + __expf(-x));
}
__device__ __forceinline__ float tanh_fast(float x) {  // x in (0,1)
    float e = __expf(-2.0f * x);
    return (1.0f - e) / (1.0f + e);
}
// transform pre-activations -> (a, b) of recurrence h = a*h + b
__device__ __forceinline__ void gate_transform(float pz, float ph, float& a, float& b) {
    float k = sigmoidf_(pz);          // k = sigmoid(x@Wz+bz)
    float z = sigmoidf_(k);           // z = sigmoid(k)   (faithful double-sigmoid)
    a = 1.0f - z;                     // exp(-softplus(k))
    float hw = tanh_fast(sigmoidf_(ph)) + EPSF;  // log_g(sigmoid(x@Wh+bh))
    b = z * hw;
}

// async global->LDS, 16B per lane; LDS dest = wave-uniform base + lane*16
__device__ __forceinline__ void gload16(const void* g, void* l) {
    __builtin_amdgcn_global_load_lds(
        (const __attribute__((address_space(1))) unsigned int*)g,
        (__attribute__((address_space(3))) unsigned int*)l, 16, 0, 0);
}

// Ordered affine compose across the 4 q-subgroups of a 64-lane wave.
// Lane's segment = (pA,pB); segment order ascending q. Returns:
//   (fA,fB)  = compose of all 4 segments (same in all lanes)
//   (prA,prB)= compose of segments with q' < q (identity for q==0)
__device__ __forceinline__ void qscan(int q, float pA, float pB,
                                      float& fA, float& fB, float& prA, float& prB)
{
    float oA = __shfl_xor(pA, 16, 64), oB = __shfl_xor(pB, 16, 64);
    float eA = (q & 1) ? oA : pA, eB = (q & 1) ? oB : pB;   // earlier of pair
    float lA = (q & 1) ? pA : oA, lB = (q & 1) ? pB : oB;   // later of pair
    float p2A = eA * lA;
    float p2B = fmaf(lA, eB, lB);
    float o2A = __shfl_xor(p2A, 32, 64), o2B = __shfl_xor(p2B, 32, 64);
    float loA = (q & 2) ? o2A : p2A, loB = (q & 2) ? o2B : p2B;
    float hiA = (q & 2) ? p2A : o2A, hiB = (q & 2) ? p2B : o2B;
    fA = loA * hiA;
    fB = fmaf(hiA, loB, hiB);
    prA = (q & 2) ? o2A : 1.0f;
    prB = (q & 2) ? o2B : 0.0f;
    if (q & 1) { prB = fmaf(oA, prB, oB); prA *= oA; }  // apply earlier-in-pair after lower pair
}

// ---------------- kx: x f32 -> fp16 -------------------------------------------
__global__ __launch_bounds__(256) void kx_conv(const float* __restrict__ x,
                                               __half* __restrict__ x16)
{
    const size_t i = ((size_t)(blockIdx.x * 256 + threadIdx.x)) * 8;
    float4 v0 = *(const float4*)&x[i];
    float4 v1 = *(const float4*)&x[i + 4];
    __half2* o = (__half2*)(x16 + i);
    o[0] = __floats2half2_rn(v0.x, v0.y);
    o[1] = __floats2half2_rn(v0.z, v0.w);
    o[2] = __floats2half2_rn(v1.x, v1.y);
    o[3] = __floats2half2_rn(v1.z, v1.w);
}

// ---------------- k0: transpose+convert W [K][512] f32 -> Wt [n][K] fp16 ----------
__global__ __launch_bounds__(256) void k0_convw(
    const float* __restrict__ W, __half* __restrict__ Wt, int ldt)
{
    __shared__ float t[64][65];
    const int n0 = blockIdx.x * 64, k0 = blockIdx.y * 64;
    const int tid = threadIdx.x;
    const int r = tid >> 4, c4 = (tid & 15) * 4;
#pragma unroll
    for (int rr = 0; rr < 64; rr += 16)
        *(float4*)&t[rr + r][c4] = *(const float4*)&W[(size_t)(k0 + rr + r) * 512 + n0 + c4];
    __syncthreads();
#pragma unroll
    for (int rr = 0; rr < 64; rr += 16) {
        const int row = rr + r;
        __half2 h01 = __floats2half2_rn(t[c4 + 0][row], t[c4 + 1][row]);
        __half2 h23 = __floats2half2_rn(t[c4 + 2][row], t[c4 + 3][row]);
        *(__half2*)&Wt[(size_t)(n0 + row) * ldt + k0 + c4] = h01;
        *(__half2*)&Wt[(size_t)(n0 + row) * ldt + k0 + c4 + 2] = h23;
    }
}

// ---------------- k1: layer-0 MFMA GEMM (K=64) --------------------------------
// MODE 0: transform + chunk summaries -> sumA/sumB
// MODE 1: transform + in-register chunk scan with carry-in -> write h0 fp16
// Block 256 thr (4 waves, 2m x 2n), tile 128m x 128n, grid (4, 512).
template<int MODE>
__global__ __launch_bounds__(256) void k1_l0(
    const __half* __restrict__ x16,
    const __half* __restrict__ Wtz, const __half* __restrict__ Wth,  // [512][64] fp16
    const float* __restrict__ bz, const float* __restrict__ bh,
    float* __restrict__ sumA, float* __restrict__ sumB,
    const float* __restrict__ carry, __half* __restrict__ h0)
{
    __shared__ __half As[128 * 64];   // [row][64k] swizzled; 16 KB
    __shared__ __half Bs[256 * 64];   // rows 0..127: z, 128..255: h; 32 KB
    const int tid = threadIdx.x;
    const int wave = tid >> 6, lane = tid & 63;
    const int q = lane >> 4, l16 = lane & 15;
    const int wm = wave >> 1, wn = wave & 1;

    // XCD-bijective swizzle: group the 4 n-tiles of each m-tile on one XCD
    const int Lb = blockIdx.x + 4 * blockIdx.y;          // 0..2047
    const int lin = (Lb & 7) * 256 + (Lb >> 3);
    const int bx = lin & 3, by = lin >> 2;
    const int m0 = by * 128, n0 = bx * 128;

    {   // stage A (16 regions x 1KB) + B (32 regions); 128B rows, 8 chunks, swz ^(row&7)
        const int r8 = lane >> 3, ch = lane & 7;
#pragma unroll
        for (int i = 0; i < 4; ++i) {
            const int reg = wave * 4 + i;
            const int row = reg * 8 + r8;
            gload16(x16 + (size_t)(m0 + row) * 64 + ((ch ^ (row & 7)) << 3),
                    (char*)As + reg * 1024);
        }
#pragma unroll
        for (int i = 0; i < 8; ++i) {
            const int reg = wave * 8 + i;
            const int row = reg * 8 + r8;
            const __half* src = (row < 128) ? (Wtz + (size_t)(n0 + row) * 64)
                                            : (Wth + (size_t)(n0 + row - 128) * 64);
            gload16(src + ((ch ^ (row & 7)) << 3), (char*)Bs + reg * 1024);
        }
    }
    __syncthreads();

    f32x4 accz[4][4], acch[4][4];
#pragma unroll
    for (int mi = 0; mi < 4; ++mi)
#pragma unroll
        for (int ni = 0; ni < 4; ++ni) {
            accz[mi][ni] = (f32x4){0.f, 0.f, 0.f, 0.f};
            acch[mi][ni] = (f32x4){0.f, 0.f, 0.f, 0.f};
        }

#pragma unroll
    for (int s = 0; s < 2; ++s) {
        half8 af[4];
#pragma unroll
        for (int mi = 0; mi < 4; ++mi) {
            const int row = wm * 64 + mi * 16 + l16;
            const int pc = (s * 4 + q) ^ (row & 7);
            af[mi] = *(const half8*)&As[row * 64 + pc * 8];
        }
#pragma unroll
        for (int ni = 0; ni < 4; ++ni) {
            const int rn = wn * 64 + ni * 16 + l16;
            const int pc = (s * 4 + q) ^ (rn & 7);
            half8 bzf = *(const half8*)&Bs[rn * 64 + pc * 8];
            half8 bhf = *(const half8*)&Bs[(128 + rn) * 64 + pc * 8];
#pragma unroll
            for (int mi = 0; mi < 4; ++mi) {
                accz[mi][ni] = __builtin_amdgcn_mfma_f32_16x16x32_f16(af[mi], bzf, accz[mi][ni], 0, 0, 0);
                acch[mi][ni] = __builtin_amdgcn_mfma_f32_16x16x32_f16(af[mi], bhf, acch[mi][ni], 0, 0, 0);
            }
        }
    }

    // epilogue. C layout: row(m) = q*4 + reg_j (+mi*16), col(n) = l16 (+ni*16)
    const int bidx = by >> 5;                    // m0>>12
    const int chunkg = ((by & 31) << 1) + wm;    // global chunk within batch
    const size_t srow = ((size_t)(bidx * 64 + chunkg)) << 9;

#pragma unroll
    for (int ni = 0; ni < 4; ++ni) {
        const int col = n0 + wn * 64 + ni * 16 + l16;
        const float bzv = bz[col], bhv = bh[col];
        if (MODE == 0) {
            float fullA = 1.f, fullB = 0.f;
#pragma unroll
            for (int mi = 0; mi < 4; ++mi) {
                float pA = 1.f, pB = 0.f;
#pragma unroll
                for (int j = 0; j < 4; ++j) {
                    float a, b;
                    gate_transform(accz[mi][ni][j] + bzv, acch[mi][ni][j] + bhv, a, b);
                    pB = fmaf(a, pB, b); pA *= a;
                }
                float fA, fB, prA, prB;
                qscan(q, pA, pB, fA, fB, prA, prB);
                fullB = fmaf(fA, fullB, fB); fullA *= fA;
            }
            if (q == 0) { sumA[srow + col] = fullA; sumB[srow + col] = fullB; }
        } else {
            float H = carry[srow + col];
#pragma unroll
            for (int mi = 0; mi < 4; ++mi) {
                float av[4], bv[4];
                float pA = 1.f, pB = 0.f;
#pragma unroll
                for (int j = 0; j < 4; ++j) {
                    gate_transform(accz[mi][ni][j] + bzv, acch[mi][ni][j] + bhv, av[j], bv[j]);
                    pB = fmaf(av[j], pB, bv[j]); pA *= av[j];
                }
                float fA, fB, prA, prB;
                qscan(q, pA, pB, fA, fB, prA, prB);
                float Hl = fmaf(prA, H, prB);        // h before this lane's 4 rows
                const int rbase = m0 + wm * 64 + mi * 16 + q * 4;
#pragma unroll
                for (int j = 0; j < 4; ++j) {
                    Hl = fmaf(av[j], Hl, bv[j]);
                    h0[(size_t)(rbase + j) * 512 + col] = (__half)Hl;
                }
                H = fmaf(fA, H, fB);                 // advance past mi-block
            }
        }
    }
}

// ---------------- k2: scan chunk summaries -> per-chunk carry-in ------------------
__global__ __launch_bounds__(256) void k2_carry(
    const float* __restrict__ sumA, const float* __restrict__ sumB,
    float* __restrict__ carry)
{
    const int idx = blockIdx.x * 256 + threadIdx.x;  // 0..8191
    const int b = idx >> 9, h = idx & 511;
    float H = EPSF;
    for (int c = 0; c < 64; ++c) {
        const size_t o = ((size_t)(b * 64 + c) << 9) + h;
        carry[o] = H;
        H = fmaf(sumA[o], H, sumB[o]);
    }
}

// ---------------- k4: layer-1 MFMA GEMM (K=512) + transform + chunk summaries -----
// Block 256 thr (4 waves, 2m x 2n), tile 128m x 128n, K_STEP 32, dbuf LDS, grid (4,512).
__global__ __launch_bounds__(256) void k4_l1(
    const __half* __restrict__ h0,
    const __half* __restrict__ Wtz, const __half* __restrict__ Wth,  // [512][512] fp16
    const float* __restrict__ bz, const float* __restrict__ bh,
    float* __restrict__ sumA, float* __restrict__ sumB)
{
    __shared__ __half As[2][128 * 32];   // 8 KB each; 64B rows, 4 chunks, swz ^((row>>1)&3)
    __shared__ __half Bs[2][256 * 32];   // 16 KB each; rows 0..127 z, 128..255 h
    const int tid = threadIdx.x;
    const int wave = tid >> 6, lane = tid & 63;
    const int q = lane >> 4, l16 = lane & 15;
    const int wm = wave >> 1, wn = wave & 1;

    const int Lb = blockIdx.x + 4 * blockIdx.y;
    const int lin = (Lb & 7) * 256 + (Lb >> 3);
    const int bx = lin & 3, by = lin >> 2;
    const int m0 = by * 128, n0 = bx * 128;

    const int r4 = lane >> 2, ch = lane & 3;

    f32x4 accz[4][4], acch[4][4];
#pragma unroll
    for (int mi = 0; mi < 4; ++mi)
#pragma unroll
        for (int ni = 0; ni < 4; ++ni) {
            accz[mi][ni] = (f32x4){0.f, 0.f, 0.f, 0.f};
            acch[mi][ni] = (f32x4){0.f, 0.f, 0.f, 0.f};
        }

    auto stage = [&](int c, int t) {
#pragma unroll
        for (int i = 0; i < 2; ++i) {          // A: 8 regions x 1KB (16 rows each)
            const int reg = wave * 2 + i;
            const int row = reg * 16 + r4;
            const int pc = ch ^ ((row >> 1) & 3);
            gload16(h0 + (size_t)(m0 + row) * 512 + t * 32 + pc * 8,
                    (char*)&As[c][0] + reg * 1024);
        }
#pragma unroll
        for (int i = 0; i < 4; ++i) {          // B: 16 regions
            const int reg = wave * 4 + i;
            const int row = reg * 16 + r4;
            const int pc = ch ^ ((row >> 1) & 3);
            const __half* src = (row < 128) ? (Wtz + (size_t)(n0 + row) * 512)
                                            : (Wth + (size_t)(n0 + row - 128) * 512);
            gload16(src + t * 32 + pc * 8, (char*)&Bs[c][0] + reg * 1024);
        }
    };

    stage(0, 0);
    __syncthreads();

    int cur = 0;
    for (int t = 0; t < 16; ++t) {
        if (t < 15) stage(cur ^ 1, t + 1);     // overlap next-tile DMA with MFMA
        half8 af[4];
#pragma unroll
        for (int mi = 0; mi < 4; ++mi) {
            const int row = wm * 64 + mi * 16 + l16;
            const int pc = q ^ ((row >> 1) & 3);
            af[mi] = *(const half8*)&As[cur][row * 32 + pc * 8];
        }
#pragma unroll
        for (int ni = 0; ni < 4; ++ni) {
            const int rn = wn * 64 + ni * 16 + l16;
            const int pc = q ^ ((rn >> 1) & 3);
            half8 bzf = *(const half8*)&Bs[cur][rn * 32 + pc * 8];
            half8 bhf = *(const half8*)&Bs[cur][(128 + rn) * 32 + pc * 8];
#pragma unroll
            for (int mi = 0; mi < 4; ++mi) {
                accz[mi][ni] = __builtin_amdgcn_mfma_f32_16x16x32_f16(af[mi], bzf, accz[mi][ni], 0, 0, 0);
                acch[mi][ni] = __builtin_amdgcn_mfma_f32_16x16x32_f16(af[mi], bhf, acch[mi][ni], 0, 0, 0);
            }
        }
        __syncthreads();                       // drains vmcnt: stage(t+1) landed; reads of cur done
        cur ^= 1;
    }

    // epilogue: transform + chunk summary (wave wm owns chunk)
    const int bidx = by >> 5;
    const int chunkg = ((by & 31) << 1) + wm;
    const size_t srow = ((size_t)(bidx * 64 + chunkg)) << 9;
#pragma unroll
    for (int ni = 0; ni < 4; ++ni) {
        const int col = n0 + wn * 64 + ni * 16 + l16;
        const float bzv = bz[col], bhv = bh[col];
        float fullA = 1.f, fullB = 0.f;
#pragma unroll
        for (int mi = 0; mi < 4; ++mi) {
            float pA = 1.f, pB = 0.f;
#pragma unroll
            for (int j = 0; j < 4; ++j) {
                float a, b;
                gate_transform(accz[mi][ni][j] + bzv, acch[mi][ni][j] + bhv, a, b);
                pB = fmaf(a, pB, b); pA *= a;
            }
            float fA, fB, prA, prB;
            qscan(q, pA, pB, fA, fB, prA, prB);
            fullB = fmaf(fA, fullB, fB); fullA *= fA;
        }
        if (q == 0) { sumA[srow + col] = fullA; sumB[srow + col] = fullB; }
    }
}

// ---------------- k5: final chunk scan + GEMV with Wf ----------------------------
__global__ __launch_bounds__(512) void k5_final(
    const float* __restrict__ sumA, const float* __restrict__ sumB,
    const float* __restrict__ Wf, const float* __restrict__ bf,
    float* __restrict__ out)
{
    const int b = blockIdx.x, h = threadIdx.x;
    float H = EPSF;
    for (int c = 0; c < 64; ++c) {
        const size_t o = ((size_t)(b * 64 + c) << 9) + h;
        H = fmaf(sumA[o], H, sumB[o]);
    }
    float v = H * Wf[h];
#pragma unroll
    for (int off = 32; off; off >>= 1) v += __shfl_down(v, off, 64);
    __shared__ float wsum[8];
    if ((h & 63) == 0) wsum[h >> 6] = v;
    __syncthreads();
    if (h == 0) {
        float s = 0.f;
#pragma unroll
        for (int i = 0; i < 8; ++i) s += wsum[i];
        out[b] = s + bf[0];
    }
}

extern "C" void kernel_launch(void* const* d_in, const int* in_sizes, int n_in,
                              void* d_out, int out_size, void* d_ws, size_t ws_size,
                              hipStream_t stream)
{
    const float* x   = (const float*)d_in[0];
    const float* Wz0 = (const float*)d_in[1];
    const float* bz0 = (const float*)d_in[2];
    const float* Wh0 = (const float*)d_in[3];
    const float* bh0 = (const float*)d_in[4];
    const float* Wz1 = (const float*)d_in[5];
    const float* bz1 = (const float*)d_in[6];
    const float* Wh1 = (const float*)d_in[7];
    const float* bh1 = (const float*)d_in[8];
    const float* Wf  = (const float*)d_in[9];
    const float* bf  = (const float*)d_in[10];
    float* out = (float*)d_out;

    // workspace layout (~80 MiB)
    char* ws = (char*)d_ws;
    __half* x16  = (__half*)ws;                          // 8 MiB
    __half* h0b  = (__half*)(ws + ((size_t)8 << 20));    // 64 MiB
    __half* Wtz1 = (__half*)(ws + ((size_t)72 << 20));   // 512 KiB
    __half* Wth1 = Wtz1 + 262144;                        // 512 KiB
    __half* Wtz0 = Wth1 + 262144;                        // 64 KiB
    __half* Wth0 = Wtz0 + 32768;                         // 64 KiB
    float* sumA  = (float*)(ws + ((size_t)74 << 20));    // 2 MiB
    float* sumB  = sumA + 524288;                        // 2 MiB
    float* carry = sumB + 524288;                        // 2 MiB

    kx_conv<<<2048, 256, 0, stream>>>(x, x16);
    k0_convw<<<dim3(8, 8), 256, 0, stream>>>(Wz1, Wtz1, 512);
    k0_convw<<<dim3(8, 8), 256, 0, stream>>>(Wh1, Wth1, 512);
    k0_convw<<<dim3(8, 1), 256, 0, stream>>>(Wz0, Wtz0, 64);
    k0_convw<<<dim3(8, 1), 256, 0, stream>>>(Wh0, Wth0, 64);
    k1_l0<0><<<dim3(4, 512), 256, 0, stream>>>(x16, Wtz0, Wth0, bz0, bh0,
                                               sumA, sumB, nullptr, nullptr);
    k2_carry<<<32, 256, 0, stream>>>(sumA, sumB, carry);
    k1_l0<1><<<dim3(4, 512), 256, 0, stream>>>(x16, Wtz0, Wth0, bz0, bh0,
                                               nullptr, nullptr, carry, h0b);
    k4_l1<<<dim3(4, 512), 256, 0, stream>>>(h0b, Wtz1, Wth1, bz1, bh1, sumA, sumB);
    k5_final<<<16, 512, 0, stream>>>(sumA, sumB, Wf, bf, out);
}